// Round 5
// baseline (64138.177 us; speedup 1.0000x reference)
//
#include <hip/hip_runtime.h>
#include <math.h>

#define HID 25
#define STR 32   // padded node-feature row stride (128B rows)
#define CHUNK 1024
#define WPAD 56  // padded LDS weight row stride (two 28-float halves, 112B-aligned)

__device__ __forceinline__ float gelu_f(float x) {
    return 0.5f * x * (1.0f + erff(x * 0.70710678118654752f));
}

// ---------------- node input linear: hn = [x,token] @ ilin_W + ilin_b ----------------
__global__ void k_node_in(const float* __restrict__ x, const float* __restrict__ token,
                          const float* __restrict__ W, const float* __restrict__ b,
                          float* __restrict__ hn, int N) {
    int gid = blockIdx.x * blockDim.x + threadIdx.x;
    int n = gid >> 5, j = gid & 31;
    if (n >= N || j >= HID) return;
    float acc = b[j];
    acc += x[n] * W[j];
    #pragma unroll
    for (int i = 0; i < 5; i++) acc += token[n * 5 + i] * W[(i + 1) * HID + j];
    hn[(size_t)n * STR + j] = acc;
}

// ---------------- edge MLP -> hard gumbel gate.
// Weights staged ONCE per block into LDS (broadcast ds_read_b128 in the inner loop);
// hidden layers in two 25-output half-passes to bound live registers. ----------
__global__ __launch_bounds__(256, 2) void k_edge_mlp(
    const int* __restrict__ ei, const float* __restrict__ x, const float* __restrict__ token,
    const float* __restrict__ attr, const float* __restrict__ gumbel,
    const float* __restrict__ W0, const float* __restrict__ b0,
    const float* __restrict__ W1, const float* __restrict__ b1,
    const float* __restrict__ W2, const float* __restrict__ b2,
    const float* __restrict__ W3, const float* __restrict__ b3,
    float* __restrict__ eval_, int E) {
    __shared__ float sW0[13 * WPAD], sW1[50 * WPAD], sW2[50 * WPAD], sW3[100];
    __shared__ float sb0[50], sb1[50], sb2[50], sb3[2];

    for (int idx = threadIdx.x; idx < 13 * WPAD; idx += 256) {
        int r = idx / WPAD, c = idx % WPAD;
        int half = c / 28, jj = c % 28;
        sW0[idx] = (jj < 25) ? W0[r * 50 + half * 25 + jj] : 0.f;
    }
    for (int idx = threadIdx.x; idx < 50 * WPAD; idx += 256) {
        int r = idx / WPAD, c = idx % WPAD;
        int half = c / 28, jj = c % 28;
        float v1 = (jj < 25) ? W1[r * 50 + half * 25 + jj] : 0.f;
        float v2 = (jj < 25) ? W2[r * 50 + half * 25 + jj] : 0.f;
        sW1[idx] = v1; sW2[idx] = v2;
    }
    for (int idx = threadIdx.x; idx < 100; idx += 256) sW3[idx] = W3[idx];
    for (int idx = threadIdx.x; idx < 50; idx += 256) {
        sb0[idx] = b0[idx]; sb1[idx] = b1[idx]; sb2[idx] = b2[idx];
    }
    if (threadIdx.x < 2) sb3[threadIdx.x] = b3[threadIdx.x];
    __syncthreads();

    int e = blockIdx.x * blockDim.x + threadIdx.x;
    if (e >= E) return;
    int s = ei[e], d = ei[E + e];

    float in[13];
    in[0] = x[s];
    #pragma unroll
    for (int i = 0; i < 5; i++) in[1 + i] = token[s * 5 + i];
    in[6] = x[d];
    #pragma unroll
    for (int i = 0; i < 5; i++) in[7 + i] = token[d * 5 + i];
    in[12] = attr[e];

    float hA[50], hB[50];

    // layer 0: 13 -> 50
    #pragma unroll
    for (int half = 0; half < 2; half++) {
        float t[25];
        #pragma unroll
        for (int jj = 0; jj < 25; jj++) t[jj] = sb0[half * 25 + jj];
        #pragma unroll
        for (int i = 0; i < 13; i++) {
            float hv = in[i];
            const float* w = &sW0[i * WPAD + half * 28];
            #pragma unroll
            for (int jj = 0; jj < 25; jj++) t[jj] += hv * w[jj];
        }
        #pragma unroll
        for (int jj = 0; jj < 25; jj++) hA[half * 25 + jj] = gelu_f(t[jj]);
    }
    // layer 1: 50 -> 50
    #pragma unroll
    for (int half = 0; half < 2; half++) {
        float t[25];
        #pragma unroll
        for (int jj = 0; jj < 25; jj++) t[jj] = sb1[half * 25 + jj];
        #pragma unroll
        for (int i = 0; i < 50; i++) {
            float hv = hA[i];
            const float* w = &sW1[i * WPAD + half * 28];
            #pragma unroll
            for (int jj = 0; jj < 25; jj++) t[jj] += hv * w[jj];
        }
        #pragma unroll
        for (int jj = 0; jj < 25; jj++) hB[half * 25 + jj] = gelu_f(t[jj]);
    }
    // layer 2: 50 -> 50
    #pragma unroll
    for (int half = 0; half < 2; half++) {
        float t[25];
        #pragma unroll
        for (int jj = 0; jj < 25; jj++) t[jj] = sb2[half * 25 + jj];
        #pragma unroll
        for (int i = 0; i < 50; i++) {
            float hv = hB[i];
            const float* w = &sW2[i * WPAD + half * 28];
            #pragma unroll
            for (int jj = 0; jj < 25; jj++) t[jj] += hv * w[jj];
        }
        #pragma unroll
        for (int jj = 0; jj < 25; jj++) hA[half * 25 + jj] = gelu_f(t[jj]);
    }
    // layer 3: 50 -> 2
    float z0 = sb3[0], z1 = sb3[1];
    #pragma unroll
    for (int i = 0; i < 50; i++) { z0 += hA[i] * sW3[i * 2]; z1 += hA[i] * sW3[i * 2 + 1]; }

    float g0 = gumbel[2 * (size_t)e], g1 = gumbel[2 * (size_t)e + 1];
    eval_[e] = (z1 + g1 > z0 + g0) ? 1.0f : 0.0f;
}

// ---------------- CSR build: histogram + scan + scatter ----------------
__global__ void k_hist(const int* __restrict__ ei, int* __restrict__ cnt, int E) {
    int e = blockIdx.x * blockDim.x + threadIdx.x;
    if (e >= E) return;
    atomicAdd(&cnt[ei[E + e]], 1);
}

__global__ void k_scan_partial(const int* __restrict__ cnt, int* __restrict__ bsum, int N) {
    __shared__ int s[256];
    int b = blockIdx.x, t = threadIdx.x;
    int base = b * CHUNK + t * 4;
    int sum = 0;
    #pragma unroll
    for (int u = 0; u < 4; u++) { int idx = base + u; if (idx < N) sum += cnt[idx]; }
    s[t] = sum; __syncthreads();
    for (int off = 128; off > 0; off >>= 1) {
        if (t < off) s[t] += s[t + off];
        __syncthreads();
    }
    if (t == 0) bsum[b] = s[0];
}

__global__ void k_scan_top(const int* __restrict__ bsum, int* __restrict__ boff,
                           int* __restrict__ rowptr, int nb, int N, int E) {
    if (threadIdx.x == 0 && blockIdx.x == 0) {
        int run = 0;
        for (int i = 0; i < nb; i++) { boff[i] = run; run += bsum[i]; }
        rowptr[N] = E;
    }
}

__global__ void k_scan_final(const int* __restrict__ cnt, const int* __restrict__ boff,
                             int* __restrict__ rowptr, int* __restrict__ wpos, int N) {
    __shared__ int s[256];
    int b = blockIdx.x, t = threadIdx.x;
    int base = b * CHUNK + t * 4;
    int v0 = 0, v1 = 0, v2 = 0, v3 = 0;
    if (base     < N) v0 = cnt[base];
    if (base + 1 < N) v1 = cnt[base + 1];
    if (base + 2 < N) v2 = cnt[base + 2];
    if (base + 3 < N) v3 = cnt[base + 3];
    int ts = v0 + v1 + v2 + v3;
    s[t] = ts; __syncthreads();
    for (int off = 1; off < 256; off <<= 1) {
        int xv = (t >= off) ? s[t - off] : 0;
        __syncthreads();
        s[t] += xv;
        __syncthreads();
    }
    int excl = s[t] - ts + boff[b];
    if (base     < N) { rowptr[base]     = excl;                 wpos[base]     = excl; }
    if (base + 1 < N) { int p = excl + v0;           rowptr[base + 1] = p; wpos[base + 1] = p; }
    if (base + 2 < N) { int p = excl + v0 + v1;      rowptr[base + 2] = p; wpos[base + 2] = p; }
    if (base + 3 < N) { int p = excl + v0 + v1 + v2; rowptr[base + 3] = p; wpos[base + 3] = p; }
}

__global__ void k_scatter(const int* __restrict__ ei, int* __restrict__ wpos,
                          int* __restrict__ col, int E) {
    int e = blockIdx.x * blockDim.x + threadIdx.x;
    if (e >= E) return;
    int d = ei[E + e];
    int p = atomicAdd(&wpos[d], 1);
    col[p] = e;
}

// ---------------- per-layer node transform: q,k,v and hnext = hn@Wskip + bskip ----------------
__global__ void k_qkvs(const float* __restrict__ hn,
                       const float* __restrict__ Wq, const float* __restrict__ bq,
                       const float* __restrict__ Wk, const float* __restrict__ bk,
                       const float* __restrict__ Wv, const float* __restrict__ bv,
                       const float* __restrict__ Ws, const float* __restrict__ bs,
                       float* __restrict__ q, float* __restrict__ k, float* __restrict__ v,
                       float* __restrict__ hnext, int N) {
    __shared__ float sWq[625], sWk[625], sWv[625], sWs[625], sbq[25], sbk[25], sbv[25], sbs[25];
    for (int i = threadIdx.x; i < 625; i += blockDim.x) {
        sWq[i] = Wq[i]; sWk[i] = Wk[i]; sWv[i] = Wv[i]; sWs[i] = Ws[i];
    }
    if (threadIdx.x < 25) {
        sbq[threadIdx.x] = bq[threadIdx.x]; sbk[threadIdx.x] = bk[threadIdx.x];
        sbv[threadIdx.x] = bv[threadIdx.x]; sbs[threadIdx.x] = bs[threadIdx.x];
    }
    __syncthreads();
    int gid = blockIdx.x * blockDim.x + threadIdx.x;
    int n = gid >> 5, j = gid & 31;
    if (n >= N || j >= HID) return;
    float h[25];
    #pragma unroll
    for (int i = 0; i < 25; i++) h[i] = hn[(size_t)n * STR + i];
    float aq = sbq[j], ak = sbk[j], av = sbv[j], as = sbs[j];
    #pragma unroll
    for (int i = 0; i < 25; i++) {
        float hi = h[i];
        aq += hi * sWq[i * 25 + j];
        ak += hi * sWk[i * 25 + j];
        av += hi * sWv[i * 25 + j];
        as += hi * sWs[i * 25 + j];
    }
    size_t o = (size_t)n * STR + j;
    q[o] = aq; k[o] = ak; v[o] = av; hnext[o] = as;
}

// ---------------- fused node-centric attention (denom + agg in one pass) ----------------
__global__ void k_attn_node(const int* __restrict__ rowptr, const int* __restrict__ col,
                            const int* __restrict__ ei,
                            const float* __restrict__ q, const float* __restrict__ kk,
                            const float* __restrict__ v, const float* __restrict__ attr,
                            const float* __restrict__ eval_,
                            const float* __restrict__ We, const float* __restrict__ be,
                            float* __restrict__ hnext, int N, int E) {
    int n = blockIdx.x * blockDim.x + threadIdx.x;
    if (n >= N) return;
    const float scale = 0.44721359549995793f;

    float qr[25];
    #pragma unroll
    for (int i = 0; i < 25; i++) qr[i] = q[(size_t)n * STR + i];

    float qW0[5], qW1[5], qbe[5];
    #pragma unroll
    for (int h = 0; h < 5; h++) {
        float a0 = 0.f, a1 = 0.f, ab = 0.f;
        #pragma unroll
        for (int c = 0; c < 5; c++) {
            int i = h * 5 + c;
            a0 += qr[i] * We[i];
            a1 += qr[i] * We[25 + i];
            ab += qr[i] * be[i];
        }
        qW0[h] = a0; qW1[h] = a1; qbe[h] = ab;
    }

    float accV[25];
    #pragma unroll
    for (int i = 0; i < 25; i++) accV[i] = 0.f;
    float den[5] = {0, 0, 0, 0, 0}, sA[5] = {0, 0, 0, 0, 0}, sG[5] = {0, 0, 0, 0, 0};

    int beg = rowptr[n], end = rowptr[n + 1];
    for (int p = beg; p < end; p++) {
        int e = col[p];
        int s = ei[e];
        float a_ = attr[e], gl = eval_[e];
        const float* kr = kk + (size_t)s * STR;
        const float* vr = v + (size_t)s * STR;
        #pragma unroll
        for (int h = 0; h < 5; h++) {
            float al = qW0[h] * a_ + qW1[h] * gl + qbe[h];
            #pragma unroll
            for (int c = 0; c < 5; c++) { int i = h * 5 + c; al += qr[i] * kr[i]; }
            float ex = expf(al * scale);
            den[h] += ex;
            sA[h] += ex * a_;
            sG[h] += ex * gl;
            #pragma unroll
            for (int c = 0; c < 5; c++) { int i = h * 5 + c; accV[i] += ex * vr[i]; }
        }
    }

    #pragma unroll
    for (int h = 0; h < 5; h++) {
        float inv = 1.f / (den[h] + 1e-16f);
        #pragma unroll
        for (int c = 0; c < 5; c++) {
            int i = h * 5 + c;
            float agg = (accV[i] + sA[h] * We[i] + sG[h] * We[25 + i] + den[h] * be[i]) * inv;
            hnext[(size_t)n * STR + i] += agg;
        }
    }
}

// ---------------- output: sigmoid(hn @ olin_W + olin_b) ----------------
__global__ void k_out(const float* __restrict__ hn, const float* __restrict__ W,
                      const float* __restrict__ b, float* __restrict__ out, int N) {
    int n = blockIdx.x * blockDim.x + threadIdx.x;
    if (n >= N) return;
    float acc = b[0];
    #pragma unroll
    for (int i = 0; i < 25; i++) acc += hn[(size_t)n * STR + i] * W[i];
    out[n] = 1.f / (1.f + expf(-acc));
}

extern "C" void kernel_launch(void* const* d_in, const int* in_sizes, int n_in,
                              void* d_out, int out_size, void* d_ws, size_t ws_size,
                              hipStream_t stream) {
    const float* x      = (const float*)d_in[0];
    const float* token  = (const float*)d_in[1];
    const float* attr   = (const float*)d_in[2];
    const float* gumbel = (const float*)d_in[3];
    const int*   ei     = (const int*)d_in[4];
    const float* W0 = (const float*)d_in[5];
    const float* b0 = (const float*)d_in[6];
    const float* W1 = (const float*)d_in[7];
    const float* b1 = (const float*)d_in[8];
    const float* W2 = (const float*)d_in[9];
    const float* b2 = (const float*)d_in[10];
    const float* W3 = (const float*)d_in[11];
    const float* b3 = (const float*)d_in[12];
    const float* ilW = (const float*)d_in[13];
    const float* ilb = (const float*)d_in[14];
    const float* Wq = (const float*)d_in[15];
    const float* bq = (const float*)d_in[16];
    const float* Wk = (const float*)d_in[17];
    const float* bk = (const float*)d_in[18];
    const float* Wv = (const float*)d_in[19];
    const float* bv = (const float*)d_in[20];
    const float* We = (const float*)d_in[21];
    const float* be = (const float*)d_in[22];
    const float* Ws = (const float*)d_in[23];
    const float* bs = (const float*)d_in[24];
    const float* oW = (const float*)d_in[25];
    const float* ob = (const float*)d_in[26];

    const int N = in_sizes[0];
    const int E = in_sizes[2];
    const int nb_chunk = (N + CHUNK - 1) / CHUNK;

    char* ws = (char*)d_ws;
    size_t off = 0;
    auto alloc = [&](size_t nb) -> void* {
        void* p = ws + off;
        off += (nb + 255) & ~(size_t)255;
        return p;
    };
    float* hnA    = (float*)alloc((size_t)N * STR * 4);
    float* hnB    = (float*)alloc((size_t)N * STR * 4);
    float* q      = (float*)alloc((size_t)N * STR * 4);
    float* k      = (float*)alloc((size_t)N * STR * 4);
    float* v      = (float*)alloc((size_t)N * STR * 4);
    float* evalv  = (float*)alloc((size_t)E * 4);
    int*   cnt    = (int*)alloc((size_t)N * 4);
    int*   rowptr = (int*)alloc((size_t)(N + 1) * 4);
    int*   wpos   = (int*)alloc((size_t)N * 4);
    int*   bsum   = (int*)alloc((size_t)(nb_chunk + 1) * 4);
    int*   boff   = (int*)alloc((size_t)(nb_chunk + 1) * 4);
    int*   col    = (int*)alloc((size_t)E * 4);

    int nb_n32 = (N * STR + 255) / 256;
    int nb_e   = (E + 255) / 256;
    int nb_n   = (N + 255) / 256;

    hipMemsetAsync(cnt, 0, (size_t)N * 4, stream);
    k_node_in<<<nb_n32, 256, 0, stream>>>(x, token, ilW, ilb, hnA, N);
    k_edge_mlp<<<nb_e, 256, 0, stream>>>(ei, x, token, attr, gumbel,
                                         W0, b0, W1, b1, W2, b2, W3, b3, evalv, E);
    k_hist<<<nb_e, 256, 0, stream>>>(ei, cnt, E);
    k_scan_partial<<<nb_chunk, 256, 0, stream>>>(cnt, bsum, N);
    k_scan_top<<<1, 64, 0, stream>>>(bsum, boff, rowptr, nb_chunk, N, E);
    k_scan_final<<<nb_chunk, 256, 0, stream>>>(cnt, boff, rowptr, wpos, N);
    k_scatter<<<nb_e, 256, 0, stream>>>(ei, wpos, col, E);

    float* cur = hnA;
    float* nxt = hnB;
    for (int l = 0; l < 3; l++) {
        k_qkvs<<<nb_n32, 256, 0, stream>>>(cur, Wq + l * 625, bq + l * 25,
                                           Wk + l * 625, bk + l * 25,
                                           Wv + l * 625, bv + l * 25,
                                           Ws + l * 625, bs + l * 25,
                                           q, k, v, nxt, N);
        k_attn_node<<<nb_n, 256, 0, stream>>>(rowptr, col, ei, q, k, v, attr, evalv,
                                              We + l * 50, be + l * 25, nxt, N, E);
        float* t = cur; cur = nxt; nxt = t;
    }
    k_out<<<nb_n, 256, 0, stream>>>(cur, oW, ob, (float*)d_out, N);
}

// Round 6
// 54498.840 us; speedup vs baseline: 1.1769x; 1.1769x over previous
//
#include <hip/hip_runtime.h>
#include <math.h>

#define HID 25
#define STR 32   // padded node-feature row stride (128B rows)
#define CHUNK 1024
#define WPAD 56  // padded LDS weight row stride (two 28-float halves, 112B-aligned)

__device__ __forceinline__ float gelu_f(float x) {
    return 0.5f * x * (1.0f + erff(x * 0.70710678118654752f));
}

// ---------------- node input linear: hn = [x,token] @ ilin_W + ilin_b ----------------
__global__ void k_node_in(const float* __restrict__ x, const float* __restrict__ token,
                          const float* __restrict__ W, const float* __restrict__ b,
                          float* __restrict__ hn, int N) {
    int gid = blockIdx.x * blockDim.x + threadIdx.x;
    int n = gid >> 5, j = gid & 31;
    if (n >= N || j >= HID) return;
    float acc = b[j];
    acc += x[n] * W[j];
    #pragma unroll
    for (int i = 0; i < 5; i++) acc += token[n * 5 + i] * W[(i + 1) * HID + j];
    hn[(size_t)n * STR + j] = acc;
}

// ---------------- edge MLP -> hard gumbel gate.
// LDS weights (broadcast reads), two 25-output half-passes.
// NO min-wave launch bound: let the allocator use ~150-200 VGPRs instead of
// spilling under a 128 cap (R5 lesson: 171 GB of scratch traffic).
__global__ __launch_bounds__(256) void k_edge_mlp(
    const int* __restrict__ ei, const float* __restrict__ x, const float* __restrict__ token,
    const float* __restrict__ attr, const float* __restrict__ gumbel,
    const float* __restrict__ W0, const float* __restrict__ b0,
    const float* __restrict__ W1, const float* __restrict__ b1,
    const float* __restrict__ W2, const float* __restrict__ b2,
    const float* __restrict__ W3, const float* __restrict__ b3,
    float* __restrict__ eval_, int E) {
    __shared__ float sW0[13 * WPAD], sW1[50 * WPAD], sW2[50 * WPAD], sW3[100];
    __shared__ float sb0[50], sb1[50], sb2[50], sb3[2];

    for (int idx = threadIdx.x; idx < 13 * WPAD; idx += 256) {
        int r = idx / WPAD, c = idx % WPAD;
        int half = c / 28, jj = c % 28;
        sW0[idx] = (jj < 25) ? W0[r * 50 + half * 25 + jj] : 0.f;
    }
    for (int idx = threadIdx.x; idx < 50 * WPAD; idx += 256) {
        int r = idx / WPAD, c = idx % WPAD;
        int half = c / 28, jj = c % 28;
        float v1 = (jj < 25) ? W1[r * 50 + half * 25 + jj] : 0.f;
        float v2 = (jj < 25) ? W2[r * 50 + half * 25 + jj] : 0.f;
        sW1[idx] = v1; sW2[idx] = v2;
    }
    for (int idx = threadIdx.x; idx < 100; idx += 256) sW3[idx] = W3[idx];
    for (int idx = threadIdx.x; idx < 50; idx += 256) {
        sb0[idx] = b0[idx]; sb1[idx] = b1[idx]; sb2[idx] = b2[idx];
    }
    if (threadIdx.x < 2) sb3[threadIdx.x] = b3[threadIdx.x];
    __syncthreads();

    int e = blockIdx.x * blockDim.x + threadIdx.x;
    if (e >= E) return;
    int s = ei[e], d = ei[E + e];

    float in[13];
    in[0] = x[s];
    #pragma unroll
    for (int i = 0; i < 5; i++) in[1 + i] = token[s * 5 + i];
    in[6] = x[d];
    #pragma unroll
    for (int i = 0; i < 5; i++) in[7 + i] = token[d * 5 + i];
    in[12] = attr[e];

    float hA[50], hB[50];

    // layer 0: 13 -> 50
    #pragma unroll
    for (int half = 0; half < 2; half++) {
        float t[25];
        #pragma unroll
        for (int jj = 0; jj < 25; jj++) t[jj] = sb0[half * 25 + jj];
        #pragma unroll
        for (int i = 0; i < 13; i++) {
            float hv = in[i];
            const float* w = &sW0[i * WPAD + half * 28];
            #pragma unroll
            for (int jj = 0; jj < 25; jj++) t[jj] += hv * w[jj];
        }
        #pragma unroll
        for (int jj = 0; jj < 25; jj++) hA[half * 25 + jj] = gelu_f(t[jj]);
        __builtin_amdgcn_sched_barrier(0);
    }
    // layer 1: 50 -> 50
    #pragma unroll
    for (int half = 0; half < 2; half++) {
        float t[25];
        #pragma unroll
        for (int jj = 0; jj < 25; jj++) t[jj] = sb1[half * 25 + jj];
        #pragma unroll
        for (int i = 0; i < 50; i++) {
            float hv = hA[i];
            const float* w = &sW1[i * WPAD + half * 28];
            #pragma unroll
            for (int jj = 0; jj < 25; jj++) t[jj] += hv * w[jj];
        }
        #pragma unroll
        for (int jj = 0; jj < 25; jj++) hB[half * 25 + jj] = gelu_f(t[jj]);
        __builtin_amdgcn_sched_barrier(0);
    }
    // layer 2: 50 -> 50
    #pragma unroll
    for (int half = 0; half < 2; half++) {
        float t[25];
        #pragma unroll
        for (int jj = 0; jj < 25; jj++) t[jj] = sb2[half * 25 + jj];
        #pragma unroll
        for (int i = 0; i < 50; i++) {
            float hv = hB[i];
            const float* w = &sW2[i * WPAD + half * 28];
            #pragma unroll
            for (int jj = 0; jj < 25; jj++) t[jj] += hv * w[jj];
        }
        #pragma unroll
        for (int jj = 0; jj < 25; jj++) hA[half * 25 + jj] = gelu_f(t[jj]);
        __builtin_amdgcn_sched_barrier(0);
    }
    // layer 3: 50 -> 2
    float z0 = sb3[0], z1 = sb3[1];
    #pragma unroll
    for (int i = 0; i < 50; i++) { z0 += hA[i] * sW3[i * 2]; z1 += hA[i] * sW3[i * 2 + 1]; }

    float g0 = gumbel[2 * (size_t)e], g1 = gumbel[2 * (size_t)e + 1];
    eval_[e] = (z1 + g1 > z0 + g0) ? 1.0f : 0.0f;
}

// ---------------- CSR build: histogram + scan + scatter ----------------
__global__ void k_hist(const int* __restrict__ ei, int* __restrict__ cnt, int E) {
    int e = blockIdx.x * blockDim.x + threadIdx.x;
    if (e >= E) return;
    atomicAdd(&cnt[ei[E + e]], 1);
}

__global__ void k_scan_partial(const int* __restrict__ cnt, int* __restrict__ bsum, int N) {
    __shared__ int s[256];
    int b = blockIdx.x, t = threadIdx.x;
    int base = b * CHUNK + t * 4;
    int sum = 0;
    #pragma unroll
    for (int u = 0; u < 4; u++) { int idx = base + u; if (idx < N) sum += cnt[idx]; }
    s[t] = sum; __syncthreads();
    for (int off = 128; off > 0; off >>= 1) {
        if (t < off) s[t] += s[t + off];
        __syncthreads();
    }
    if (t == 0) bsum[b] = s[0];
}

__global__ void k_scan_top(const int* __restrict__ bsum, int* __restrict__ boff,
                           int* __restrict__ rowptr, int nb, int N, int E) {
    if (threadIdx.x == 0 && blockIdx.x == 0) {
        int run = 0;
        for (int i = 0; i < nb; i++) { boff[i] = run; run += bsum[i]; }
        rowptr[N] = E;
    }
}

__global__ void k_scan_final(const int* __restrict__ cnt, const int* __restrict__ boff,
                             int* __restrict__ rowptr, int* __restrict__ wpos, int N) {
    __shared__ int s[256];
    int b = blockIdx.x, t = threadIdx.x;
    int base = b * CHUNK + t * 4;
    int v0 = 0, v1 = 0, v2 = 0, v3 = 0;
    if (base     < N) v0 = cnt[base];
    if (base + 1 < N) v1 = cnt[base + 1];
    if (base + 2 < N) v2 = cnt[base + 2];
    if (base + 3 < N) v3 = cnt[base + 3];
    int ts = v0 + v1 + v2 + v3;
    s[t] = ts; __syncthreads();
    for (int off = 1; off < 256; off <<= 1) {
        int xv = (t >= off) ? s[t - off] : 0;
        __syncthreads();
        s[t] += xv;
        __syncthreads();
    }
    int excl = s[t] - ts + boff[b];
    if (base     < N) { rowptr[base]     = excl;                 wpos[base]     = excl; }
    if (base + 1 < N) { int p = excl + v0;           rowptr[base + 1] = p; wpos[base + 1] = p; }
    if (base + 2 < N) { int p = excl + v0 + v1;      rowptr[base + 2] = p; wpos[base + 2] = p; }
    if (base + 3 < N) { int p = excl + v0 + v1 + v2; rowptr[base + 3] = p; wpos[base + 3] = p; }
}

__global__ void k_scatter(const int* __restrict__ ei, int* __restrict__ wpos,
                          int* __restrict__ col, int E) {
    int e = blockIdx.x * blockDim.x + threadIdx.x;
    if (e >= E) return;
    int d = ei[E + e];
    int p = atomicAdd(&wpos[d], 1);
    col[p] = e;
}

// ---------------- per-layer node transform: q,k,v and hnext = hn@Wskip + bskip ----------------
__global__ void k_qkvs(const float* __restrict__ hn,
                       const float* __restrict__ Wq, const float* __restrict__ bq,
                       const float* __restrict__ Wk, const float* __restrict__ bk,
                       const float* __restrict__ Wv, const float* __restrict__ bv,
                       const float* __restrict__ Ws, const float* __restrict__ bs,
                       float* __restrict__ q, float* __restrict__ k, float* __restrict__ v,
                       float* __restrict__ hnext, int N) {
    __shared__ float sWq[625], sWk[625], sWv[625], sWs[625], sbq[25], sbk[25], sbv[25], sbs[25];
    for (int i = threadIdx.x; i < 625; i += blockDim.x) {
        sWq[i] = Wq[i]; sWk[i] = Wk[i]; sWv[i] = Wv[i]; sWs[i] = Ws[i];
    }
    if (threadIdx.x < 25) {
        sbq[threadIdx.x] = bq[threadIdx.x]; sbk[threadIdx.x] = bk[threadIdx.x];
        sbv[threadIdx.x] = bv[threadIdx.x]; sbs[threadIdx.x] = bs[threadIdx.x];
    }
    __syncthreads();
    int gid = blockIdx.x * blockDim.x + threadIdx.x;
    int n = gid >> 5, j = gid & 31;
    if (n >= N || j >= HID) return;
    float h[25];
    #pragma unroll
    for (int i = 0; i < 25; i++) h[i] = hn[(size_t)n * STR + i];
    float aq = sbq[j], ak = sbk[j], av = sbv[j], as = sbs[j];
    #pragma unroll
    for (int i = 0; i < 25; i++) {
        float hi = h[i];
        aq += hi * sWq[i * 25 + j];
        ak += hi * sWk[i * 25 + j];
        av += hi * sWv[i * 25 + j];
        as += hi * sWs[i * 25 + j];
    }
    size_t o = (size_t)n * STR + j;
    q[o] = aq; k[o] = ak; v[o] = av; hnext[o] = as;
}

// ---------------- fused node-centric attention (denom + agg in one pass) ----------------
__global__ void k_attn_node(const int* __restrict__ rowptr, const int* __restrict__ col,
                            const int* __restrict__ ei,
                            const float* __restrict__ q, const float* __restrict__ kk,
                            const float* __restrict__ v, const float* __restrict__ attr,
                            const float* __restrict__ eval_,
                            const float* __restrict__ We, const float* __restrict__ be,
                            float* __restrict__ hnext, int N, int E) {
    int n = blockIdx.x * blockDim.x + threadIdx.x;
    if (n >= N) return;
    const float scale = 0.44721359549995793f;

    float qr[25];
    #pragma unroll
    for (int i = 0; i < 25; i++) qr[i] = q[(size_t)n * STR + i];

    float qW0[5], qW1[5], qbe[5];
    #pragma unroll
    for (int h = 0; h < 5; h++) {
        float a0 = 0.f, a1 = 0.f, ab = 0.f;
        #pragma unroll
        for (int c = 0; c < 5; c++) {
            int i = h * 5 + c;
            a0 += qr[i] * We[i];
            a1 += qr[i] * We[25 + i];
            ab += qr[i] * be[i];
        }
        qW0[h] = a0; qW1[h] = a1; qbe[h] = ab;
    }

    float accV[25];
    #pragma unroll
    for (int i = 0; i < 25; i++) accV[i] = 0.f;
    float den[5] = {0, 0, 0, 0, 0}, sA[5] = {0, 0, 0, 0, 0}, sG[5] = {0, 0, 0, 0, 0};

    int beg = rowptr[n], end = rowptr[n + 1];
    for (int p = beg; p < end; p++) {
        int e = col[p];
        int s = ei[e];
        float a_ = attr[e], gl = eval_[e];
        const float* kr = kk + (size_t)s * STR;
        const float* vr = v + (size_t)s * STR;
        #pragma unroll
        for (int h = 0; h < 5; h++) {
            float al = qW0[h] * a_ + qW1[h] * gl + qbe[h];
            #pragma unroll
            for (int c = 0; c < 5; c++) { int i = h * 5 + c; al += qr[i] * kr[i]; }
            float ex = expf(al * scale);
            den[h] += ex;
            sA[h] += ex * a_;
            sG[h] += ex * gl;
            #pragma unroll
            for (int c = 0; c < 5; c++) { int i = h * 5 + c; accV[i] += ex * vr[i]; }
        }
    }

    #pragma unroll
    for (int h = 0; h < 5; h++) {
        float inv = 1.f / (den[h] + 1e-16f);
        #pragma unroll
        for (int c = 0; c < 5; c++) {
            int i = h * 5 + c;
            float agg = (accV[i] + sA[h] * We[i] + sG[h] * We[25 + i] + den[h] * be[i]) * inv;
            hnext[(size_t)n * STR + i] += agg;
        }
    }
}

// ---------------- output: sigmoid(hn @ olin_W + olin_b) ----------------
__global__ void k_out(const float* __restrict__ hn, const float* __restrict__ W,
                      const float* __restrict__ b, float* __restrict__ out, int N) {
    int n = blockIdx.x * blockDim.x + threadIdx.x;
    if (n >= N) return;
    float acc = b[0];
    #pragma unroll
    for (int i = 0; i < 25; i++) acc += hn[(size_t)n * STR + i] * W[i];
    out[n] = 1.f / (1.f + expf(-acc));
}

extern "C" void kernel_launch(void* const* d_in, const int* in_sizes, int n_in,
                              void* d_out, int out_size, void* d_ws, size_t ws_size,
                              hipStream_t stream) {
    const float* x      = (const float*)d_in[0];
    const float* token  = (const float*)d_in[1];
    const float* attr   = (const float*)d_in[2];
    const float* gumbel = (const float*)d_in[3];
    const int*   ei     = (const int*)d_in[4];
    const float* W0 = (const float*)d_in[5];
    const float* b0 = (const float*)d_in[6];
    const float* W1 = (const float*)d_in[7];
    const float* b1 = (const float*)d_in[8];
    const float* W2 = (const float*)d_in[9];
    const float* b2 = (const float*)d_in[10];
    const float* W3 = (const float*)d_in[11];
    const float* b3 = (const float*)d_in[12];
    const float* ilW = (const float*)d_in[13];
    const float* ilb = (const float*)d_in[14];
    const float* Wq = (const float*)d_in[15];
    const float* bq = (const float*)d_in[16];
    const float* Wk = (const float*)d_in[17];
    const float* bk = (const float*)d_in[18];
    const float* Wv = (const float*)d_in[19];
    const float* bv = (const float*)d_in[20];
    const float* We = (const float*)d_in[21];
    const float* be = (const float*)d_in[22];
    const float* Ws = (const float*)d_in[23];
    const float* bs = (const float*)d_in[24];
    const float* oW = (const float*)d_in[25];
    const float* ob = (const float*)d_in[26];

    const int N = in_sizes[0];
    const int E = in_sizes[2];
    const int nb_chunk = (N + CHUNK - 1) / CHUNK;

    char* ws = (char*)d_ws;
    size_t off = 0;
    auto alloc = [&](size_t nb) -> void* {
        void* p = ws + off;
        off += (nb + 255) & ~(size_t)255;
        return p;
    };
    float* hnA    = (float*)alloc((size_t)N * STR * 4);
    float* hnB    = (float*)alloc((size_t)N * STR * 4);
    float* q      = (float*)alloc((size_t)N * STR * 4);
    float* k      = (float*)alloc((size_t)N * STR * 4);
    float* v      = (float*)alloc((size_t)N * STR * 4);
    float* evalv  = (float*)alloc((size_t)E * 4);
    int*   cnt    = (int*)alloc((size_t)N * 4);
    int*   rowptr = (int*)alloc((size_t)(N + 1) * 4);
    int*   wpos   = (int*)alloc((size_t)N * 4);
    int*   bsum   = (int*)alloc((size_t)(nb_chunk + 1) * 4);
    int*   boff   = (int*)alloc((size_t)(nb_chunk + 1) * 4);
    int*   col    = (int*)alloc((size_t)E * 4);

    int nb_n32 = (N * STR + 255) / 256;
    int nb_e   = (E + 255) / 256;
    int nb_n   = (N + 255) / 256;

    hipMemsetAsync(cnt, 0, (size_t)N * 4, stream);
    k_node_in<<<nb_n32, 256, 0, stream>>>(x, token, ilW, ilb, hnA, N);
    k_edge_mlp<<<nb_e, 256, 0, stream>>>(ei, x, token, attr, gumbel,
                                         W0, b0, W1, b1, W2, b2, W3, b3, evalv, E);
    k_hist<<<nb_e, 256, 0, stream>>>(ei, cnt, E);
    k_scan_partial<<<nb_chunk, 256, 0, stream>>>(cnt, bsum, N);
    k_scan_top<<<1, 64, 0, stream>>>(bsum, boff, rowptr, nb_chunk, N, E);
    k_scan_final<<<nb_chunk, 256, 0, stream>>>(cnt, boff, rowptr, wpos, N);
    k_scatter<<<nb_e, 256, 0, stream>>>(ei, wpos, col, E);

    float* cur = hnA;
    float* nxt = hnB;
    for (int l = 0; l < 3; l++) {
        k_qkvs<<<nb_n32, 256, 0, stream>>>(cur, Wq + l * 625, bq + l * 25,
                                           Wk + l * 625, bk + l * 25,
                                           Wv + l * 625, bv + l * 25,
                                           Ws + l * 625, bs + l * 25,
                                           q, k, v, nxt, N);
        k_attn_node<<<nb_n, 256, 0, stream>>>(rowptr, col, ei, q, k, v, attr, evalv,
                                              We + l * 50, be + l * 25, nxt, N, E);
        float* t = cur; cur = nxt; nxt = t;
    }
    k_out<<<nb_n, 256, 0, stream>>>(cur, oW, ob, (float*)d_out, N);
}

// Round 7
// 3657.763 us; speedup vs baseline: 17.5348x; 14.8995x over previous
//
#include <hip/hip_runtime.h>
#include <math.h>

#define HID 25
#define STR 32   // padded node-feature row stride (128B rows)
#define CHUNK 1024

__device__ __forceinline__ float gelu_f(float x) {
    return 0.5f * x * (1.0f + erff(x * 0.70710678118654752f));
}

// ---------------- node input linear: hn = [x,token] @ ilin_W + ilin_b ----------------
__global__ void k_node_in(const float* __restrict__ x, const float* __restrict__ token,
                          const float* __restrict__ W, const float* __restrict__ b,
                          float* __restrict__ hn, int N) {
    int gid = blockIdx.x * blockDim.x + threadIdx.x;
    int n = gid >> 5, j = gid & 31;
    if (n >= N || j >= HID) return;
    float acc = b[j];
    acc += x[n] * W[j];
    #pragma unroll
    for (int i = 0; i < 5; i++) acc += token[n * 5 + i] * W[(i + 1) * HID + j];
    hn[(size_t)n * STR + j] = acc;
}

// ---------------- edge MLP, version B: lane j = output neuron j.
// Weight COLUMNS live in per-lane registers (literal-indexed, loaded once per wave);
// activations exchanged via tiny per-wave LDS ping-pong buffers (broadcast float4 reads).
// Two edges per wave-pass. Logit-diff via shfl tree; knife-edge margins (<1e-4)
// recomputed serially in reference order. ----------------
__global__ __launch_bounds__(256) void k_edge_mlp_b(
    const int* __restrict__ ei, const float* __restrict__ x, const float* __restrict__ token,
    const float* __restrict__ attr, const float* __restrict__ gumbel,
    const float* __restrict__ W0, const float* __restrict__ b0,
    const float* __restrict__ W1, const float* __restrict__ b1,
    const float* __restrict__ W2, const float* __restrict__ b2,
    const float* __restrict__ W3, const float* __restrict__ b3,
    float* __restrict__ eval_, int E, int nwaves) {
    __shared__ float buf[4][2][2][64];   // [wave][pingpong][edge][neuron]
    const int lane = threadIdx.x & 63;
    const int wv = threadIdx.x >> 6;
    const int wid = blockIdx.x * 4 + wv;
    const int jw = (lane < 50) ? lane : 49;

    float w0r[16], w1r[52], w2r[52];
    #pragma unroll
    for (int k = 0; k < 13; k++) w0r[k] = W0[k * 50 + jw];
    w0r[13] = 0.f; w0r[14] = 0.f; w0r[15] = 0.f;
    #pragma unroll
    for (int k = 0; k < 50; k++) w1r[k] = W1[k * 50 + jw];
    w1r[50] = 0.f; w1r[51] = 0.f;
    #pragma unroll
    for (int k = 0; k < 50; k++) w2r[k] = W2[k * 50 + jw];
    w2r[50] = 0.f; w2r[51] = 0.f;
    const float b0r = b0[jw], b1r = b1[jw], b2r = b2[jw];
    const float b3_0 = b3[0], b3_1 = b3[1];
    const float w3d = (lane < 50) ? (W3[lane * 2 + 1] - W3[lane * 2]) : 0.f;

    const int g = lane >> 4, r = lane & 15;

    for (long long base = (long long)wid * 2; base < E; base += (long long)nwaves * 2) {
        const int eA = (int)base;
        const int eB = eA + 1;

        // ---- gather inputs for both edges into buf[wv][0][g][0..15] ----
        if (g < 2) {
            int e = eA + g;
            float val = 0.f;
            if (e < E && r < 13) {
                if (r == 12) val = attr[e];
                else if (r < 6) { int s_ = ei[e];     val = (r == 0) ? x[s_] : token[s_ * 5 + (r - 1)]; }
                else            { int d_ = ei[E + e]; val = (r == 6) ? x[d_] : token[d_ * 5 + (r - 7)]; }
            }
            buf[wv][0][g][r] = val;
        }

        // ---- layer 0: 13 -> 50 ----
        const float4* a4 = (const float4*)(&buf[wv][0][0][0]);
        const float4* c4 = (const float4*)(&buf[wv][0][1][0]);
        float tA = b0r, tB = b0r;
        #pragma unroll
        for (int c = 0; c < 4; c++) {
            float4 a = a4[c], b = c4[c];
            tA += a.x * w0r[4 * c];     tB += b.x * w0r[4 * c];
            tA += a.y * w0r[4 * c + 1]; tB += b.y * w0r[4 * c + 1];
            tA += a.z * w0r[4 * c + 2]; tB += b.z * w0r[4 * c + 2];
            tA += a.w * w0r[4 * c + 3]; tB += b.w * w0r[4 * c + 3];
        }
        buf[wv][1][0][lane] = gelu_f(tA);
        buf[wv][1][1][lane] = gelu_f(tB);

        // ---- layer 1: 50 -> 50 ----
        const float4* p4 = (const float4*)(&buf[wv][1][0][0]);
        const float4* q4 = (const float4*)(&buf[wv][1][1][0]);
        tA = b1r; tB = b1r;
        #pragma unroll
        for (int c = 0; c < 13; c++) {
            float4 a = p4[c], b = q4[c];
            tA += a.x * w1r[4 * c];     tB += b.x * w1r[4 * c];
            tA += a.y * w1r[4 * c + 1]; tB += b.y * w1r[4 * c + 1];
            tA += a.z * w1r[4 * c + 2]; tB += b.z * w1r[4 * c + 2];
            tA += a.w * w1r[4 * c + 3]; tB += b.w * w1r[4 * c + 3];
        }
        buf[wv][0][0][lane] = gelu_f(tA);
        buf[wv][0][1][lane] = gelu_f(tB);

        // ---- layer 2: 50 -> 50 ----
        tA = b2r; tB = b2r;
        #pragma unroll
        for (int c = 0; c < 13; c++) {
            float4 a = a4[c], b = c4[c];
            tA += a.x * w2r[4 * c];     tB += b.x * w2r[4 * c];
            tA += a.y * w2r[4 * c + 1]; tB += b.y * w2r[4 * c + 1];
            tA += a.z * w2r[4 * c + 2]; tB += b.z * w2r[4 * c + 2];
            tA += a.w * w2r[4 * c + 3]; tB += b.w * w2r[4 * c + 3];
        }
        float h3A = gelu_f(tA), h3B = gelu_f(tB);
        buf[wv][1][0][lane] = h3A;   // stash for rare serial fallback
        buf[wv][1][1][lane] = h3B;

        // ---- layer 3 diff + wave reduce ----
        float zA = h3A * w3d, zB = h3B * w3d;
        #pragma unroll
        for (int off = 32; off > 0; off >>= 1) {
            zA += __shfl_xor(zA, off);
            zB += __shfl_xor(zB, off);
        }

        if (lane < 2) {
            int e = (lane == 0) ? eA : eB;
            float z = (lane == 0) ? zA : zB;
            if (e < E) {
                float g0v = gumbel[2 * (long long)e], g1v = gumbel[2 * (long long)e + 1];
                float m = z + (b3_1 - b3_0) + g1v - g0v;
                float dec;
                if (fabsf(m) < 1e-4f) {
                    float z0 = 0.f, z1 = 0.f;
                    for (int j = 0; j < 50; j++) {
                        float h = buf[wv][1][lane][j];
                        z0 += h * W3[2 * j];
                        z1 += h * W3[2 * j + 1];
                    }
                    z0 += b3_0; z1 += b3_1;
                    dec = (z1 + g1v > z0 + g0v) ? 1.f : 0.f;
                } else {
                    dec = (m > 0.f) ? 1.f : 0.f;
                }
                eval_[e] = dec;
            }
        }
    }
}

// ---------------- CSR build: histogram + scan + scatter ----------------
__global__ void k_hist(const int* __restrict__ ei, int* __restrict__ cnt, int E) {
    int e = blockIdx.x * blockDim.x + threadIdx.x;
    if (e >= E) return;
    atomicAdd(&cnt[ei[E + e]], 1);
}

__global__ void k_scan_partial(const int* __restrict__ cnt, int* __restrict__ bsum, int N) {
    __shared__ int s[256];
    int b = blockIdx.x, t = threadIdx.x;
    int base = b * CHUNK + t * 4;
    int sum = 0;
    #pragma unroll
    for (int u = 0; u < 4; u++) { int idx = base + u; if (idx < N) sum += cnt[idx]; }
    s[t] = sum; __syncthreads();
    for (int off = 128; off > 0; off >>= 1) {
        if (t < off) s[t] += s[t + off];
        __syncthreads();
    }
    if (t == 0) bsum[b] = s[0];
}

__global__ void k_scan_top(const int* __restrict__ bsum, int* __restrict__ boff,
                           int* __restrict__ rowptr, int nb, int N, int E) {
    if (threadIdx.x == 0 && blockIdx.x == 0) {
        int run = 0;
        for (int i = 0; i < nb; i++) { boff[i] = run; run += bsum[i]; }
        rowptr[N] = E;
    }
}

__global__ void k_scan_final(const int* __restrict__ cnt, const int* __restrict__ boff,
                             int* __restrict__ rowptr, int* __restrict__ wpos, int N) {
    __shared__ int s[256];
    int b = blockIdx.x, t = threadIdx.x;
    int base = b * CHUNK + t * 4;
    int v0 = 0, v1 = 0, v2 = 0, v3 = 0;
    if (base     < N) v0 = cnt[base];
    if (base + 1 < N) v1 = cnt[base + 1];
    if (base + 2 < N) v2 = cnt[base + 2];
    if (base + 3 < N) v3 = cnt[base + 3];
    int ts = v0 + v1 + v2 + v3;
    s[t] = ts; __syncthreads();
    for (int off = 1; off < 256; off <<= 1) {
        int xv = (t >= off) ? s[t - off] : 0;
        __syncthreads();
        s[t] += xv;
        __syncthreads();
    }
    int excl = s[t] - ts + boff[b];
    if (base     < N) { rowptr[base]     = excl;                 wpos[base]     = excl; }
    if (base + 1 < N) { int p = excl + v0;           rowptr[base + 1] = p; wpos[base + 1] = p; }
    if (base + 2 < N) { int p = excl + v0 + v1;      rowptr[base + 2] = p; wpos[base + 2] = p; }
    if (base + 3 < N) { int p = excl + v0 + v1 + v2; rowptr[base + 3] = p; wpos[base + 3] = p; }
}

__global__ void k_scatter(const int* __restrict__ ei, int* __restrict__ wpos,
                          int* __restrict__ col, int E) {
    int e = blockIdx.x * blockDim.x + threadIdx.x;
    if (e >= E) return;
    int d = ei[E + e];
    int p = atomicAdd(&wpos[d], 1);
    col[p] = e;
}

// ---------------- per-layer node transform: q,k,v and hnext = hn@Wskip + bskip ----------------
__global__ void k_qkvs(const float* __restrict__ hn,
                       const float* __restrict__ Wq, const float* __restrict__ bq,
                       const float* __restrict__ Wk, const float* __restrict__ bk,
                       const float* __restrict__ Wv, const float* __restrict__ bv,
                       const float* __restrict__ Ws, const float* __restrict__ bs,
                       float* __restrict__ q, float* __restrict__ k, float* __restrict__ v,
                       float* __restrict__ hnext, int N) {
    __shared__ float sWq[625], sWk[625], sWv[625], sWs[625], sbq[25], sbk[25], sbv[25], sbs[25];
    for (int i = threadIdx.x; i < 625; i += blockDim.x) {
        sWq[i] = Wq[i]; sWk[i] = Wk[i]; sWv[i] = Wv[i]; sWs[i] = Ws[i];
    }
    if (threadIdx.x < 25) {
        sbq[threadIdx.x] = bq[threadIdx.x]; sbk[threadIdx.x] = bk[threadIdx.x];
        sbv[threadIdx.x] = bv[threadIdx.x]; sbs[threadIdx.x] = bs[threadIdx.x];
    }
    __syncthreads();
    int gid = blockIdx.x * blockDim.x + threadIdx.x;
    int n = gid >> 5, j = gid & 31;
    if (n >= N || j >= HID) return;
    float h[25];
    #pragma unroll
    for (int i = 0; i < 25; i++) h[i] = hn[(size_t)n * STR + i];
    float aq = sbq[j], ak = sbk[j], av = sbv[j], as = sbs[j];
    #pragma unroll
    for (int i = 0; i < 25; i++) {
        float hi = h[i];
        aq += hi * sWq[i * 25 + j];
        ak += hi * sWk[i * 25 + j];
        av += hi * sWv[i * 25 + j];
        as += hi * sWs[i * 25 + j];
    }
    size_t o = (size_t)n * STR + j;
    q[o] = aq; k[o] = ak; v[o] = av; hnext[o] = as;
}

// ---------------- fused node-centric attention (denom + agg in one pass) ----------------
__global__ void k_attn_node(const int* __restrict__ rowptr, const int* __restrict__ col,
                            const int* __restrict__ ei,
                            const float* __restrict__ q, const float* __restrict__ kk,
                            const float* __restrict__ v, const float* __restrict__ attr,
                            const float* __restrict__ eval_,
                            const float* __restrict__ We, const float* __restrict__ be,
                            float* __restrict__ hnext, int N, int E) {
    int n = blockIdx.x * blockDim.x + threadIdx.x;
    if (n >= N) return;
    const float scale = 0.44721359549995793f;

    float qr[25];
    #pragma unroll
    for (int i = 0; i < 25; i++) qr[i] = q[(size_t)n * STR + i];

    float qW0[5], qW1[5], qbe[5];
    #pragma unroll
    for (int h = 0; h < 5; h++) {
        float a0 = 0.f, a1 = 0.f, ab = 0.f;
        #pragma unroll
        for (int c = 0; c < 5; c++) {
            int i = h * 5 + c;
            a0 += qr[i] * We[i];
            a1 += qr[i] * We[25 + i];
            ab += qr[i] * be[i];
        }
        qW0[h] = a0; qW1[h] = a1; qbe[h] = ab;
    }

    float accV[25];
    #pragma unroll
    for (int i = 0; i < 25; i++) accV[i] = 0.f;
    float den[5] = {0, 0, 0, 0, 0}, sA[5] = {0, 0, 0, 0, 0}, sG[5] = {0, 0, 0, 0, 0};

    int beg = rowptr[n], end = rowptr[n + 1];
    for (int p = beg; p < end; p++) {
        int e = col[p];
        int s = ei[e];
        float a_ = attr[e], gl = eval_[e];
        const float* kr = kk + (size_t)s * STR;
        const float* vr = v + (size_t)s * STR;
        #pragma unroll
        for (int h = 0; h < 5; h++) {
            float al = qW0[h] * a_ + qW1[h] * gl + qbe[h];
            #pragma unroll
            for (int c = 0; c < 5; c++) { int i = h * 5 + c; al += qr[i] * kr[i]; }
            float ex = expf(al * scale);
            den[h] += ex;
            sA[h] += ex * a_;
            sG[h] += ex * gl;
            #pragma unroll
            for (int c = 0; c < 5; c++) { int i = h * 5 + c; accV[i] += ex * vr[i]; }
        }
    }

    #pragma unroll
    for (int h = 0; h < 5; h++) {
        float inv = 1.f / (den[h] + 1e-16f);
        #pragma unroll
        for (int c = 0; c < 5; c++) {
            int i = h * 5 + c;
            float agg = (accV[i] + sA[h] * We[i] + sG[h] * We[25 + i] + den[h] * be[i]) * inv;
            hnext[(size_t)n * STR + i] += agg;
        }
    }
}

// ---------------- output: sigmoid(hn @ olin_W + olin_b) ----------------
__global__ void k_out(const float* __restrict__ hn, const float* __restrict__ W,
                      const float* __restrict__ b, float* __restrict__ out, int N) {
    int n = blockIdx.x * blockDim.x + threadIdx.x;
    if (n >= N) return;
    float acc = b[0];
    #pragma unroll
    for (int i = 0; i < 25; i++) acc += hn[(size_t)n * STR + i] * W[i];
    out[n] = 1.f / (1.f + expf(-acc));
}

extern "C" void kernel_launch(void* const* d_in, const int* in_sizes, int n_in,
                              void* d_out, int out_size, void* d_ws, size_t ws_size,
                              hipStream_t stream) {
    const float* x      = (const float*)d_in[0];
    const float* token  = (const float*)d_in[1];
    const float* attr   = (const float*)d_in[2];
    const float* gumbel = (const float*)d_in[3];
    const int*   ei     = (const int*)d_in[4];
    const float* W0 = (const float*)d_in[5];
    const float* b0 = (const float*)d_in[6];
    const float* W1 = (const float*)d_in[7];
    const float* b1 = (const float*)d_in[8];
    const float* W2 = (const float*)d_in[9];
    const float* b2 = (const float*)d_in[10];
    const float* W3 = (const float*)d_in[11];
    const float* b3 = (const float*)d_in[12];
    const float* ilW = (const float*)d_in[13];
    const float* ilb = (const float*)d_in[14];
    const float* Wq = (const float*)d_in[15];
    const float* bq = (const float*)d_in[16];
    const float* Wk = (const float*)d_in[17];
    const float* bk = (const float*)d_in[18];
    const float* Wv = (const float*)d_in[19];
    const float* bv = (const float*)d_in[20];
    const float* We = (const float*)d_in[21];
    const float* be = (const float*)d_in[22];
    const float* Ws = (const float*)d_in[23];
    const float* bs = (const float*)d_in[24];
    const float* oW = (const float*)d_in[25];
    const float* ob = (const float*)d_in[26];

    const int N = in_sizes[0];
    const int E = in_sizes[2];
    const int nb_chunk = (N + CHUNK - 1) / CHUNK;

    char* ws = (char*)d_ws;
    size_t off = 0;
    auto alloc = [&](size_t nb) -> void* {
        void* p = ws + off;
        off += (nb + 255) & ~(size_t)255;
        return p;
    };
    float* hnA    = (float*)alloc((size_t)N * STR * 4);
    float* hnB    = (float*)alloc((size_t)N * STR * 4);
    float* q      = (float*)alloc((size_t)N * STR * 4);
    float* k      = (float*)alloc((size_t)N * STR * 4);
    float* v      = (float*)alloc((size_t)N * STR * 4);
    float* evalv  = (float*)alloc((size_t)E * 4);
    int*   cnt    = (int*)alloc((size_t)N * 4);
    int*   rowptr = (int*)alloc((size_t)(N + 1) * 4);
    int*   wpos   = (int*)alloc((size_t)N * 4);
    int*   bsum   = (int*)alloc((size_t)(nb_chunk + 1) * 4);
    int*   boff   = (int*)alloc((size_t)(nb_chunk + 1) * 4);
    int*   col    = (int*)alloc((size_t)E * 4);

    int nb_n32 = (N * STR + 255) / 256;
    int nb_e   = (E + 255) / 256;
    int nb_n   = (N + 255) / 256;

    const int mlp_blocks = 2048;
    const int mlp_waves  = mlp_blocks * 4;

    hipMemsetAsync(cnt, 0, (size_t)N * 4, stream);
    k_node_in<<<nb_n32, 256, 0, stream>>>(x, token, ilW, ilb, hnA, N);
    k_edge_mlp_b<<<mlp_blocks, 256, 0, stream>>>(ei, x, token, attr, gumbel,
                                                 W0, b0, W1, b1, W2, b2, W3, b3,
                                                 evalv, E, mlp_waves);
    k_hist<<<nb_e, 256, 0, stream>>>(ei, cnt, E);
    k_scan_partial<<<nb_chunk, 256, 0, stream>>>(cnt, bsum, N);
    k_scan_top<<<1, 64, 0, stream>>>(bsum, boff, rowptr, nb_chunk, N, E);
    k_scan_final<<<nb_chunk, 256, 0, stream>>>(cnt, boff, rowptr, wpos, N);
    k_scatter<<<nb_e, 256, 0, stream>>>(ei, wpos, col, E);

    float* cur = hnA;
    float* nxt = hnB;
    for (int l = 0; l < 3; l++) {
        k_qkvs<<<nb_n32, 256, 0, stream>>>(cur, Wq + l * 625, bq + l * 25,
                                           Wk + l * 625, bk + l * 25,
                                           Wv + l * 625, bv + l * 25,
                                           Ws + l * 625, bs + l * 25,
                                           q, k, v, nxt, N);
        k_attn_node<<<nb_n, 256, 0, stream>>>(rowptr, col, ei, q, k, v, attr, evalv,
                                              We + l * 50, be + l * 25, nxt, N, E);
        float* t = cur; cur = nxt; nxt = t;
    }
    k_out<<<nb_n, 256, 0, stream>>>(cur, oW, ob, (float*)d_out, N);
}